// Round 5
// baseline (235.680 us; speedup 1.0000x reference)
//
#include <hip/hip_runtime.h>
#include <stdint.h>

typedef _Float16 f16x2 __attribute__((ext_vector_type(2)));
typedef _Float16 f16x8 __attribute__((ext_vector_type(8)));
typedef float f32x4 __attribute__((ext_vector_type(4)));

static __device__ __forceinline__ uint32_t perm(uint32_t hi, uint32_t lo, uint32_t sel) {
    return __builtin_amdgcn_perm(hi, lo, sel);
}
static __device__ __forceinline__ f16x2 bch2(uint32_t u) { union { uint32_t x; f16x2 h; } c; c.x = u; return c.h; }
static __device__ __forceinline__ uint32_t bcu(f16x2 h) { union { uint32_t x; f16x2 h; } c; c.h = h; return c.x; }
// cvt_pkrtz returns __fp16x2 (distinct from _Float16x2) — bit-cast through its own type
static __device__ __forceinline__ uint32_t pkrtz(float a, float b) {
    auto r = __builtin_amdgcn_cvt_pkrtz(a, b);
    union { decltype(r) h; uint32_t u; } c; c.h = r; return c.u;
}

#define NTOT 8192
#define KTOT 8192
#define SPLITS 16
#define KCHUNK 512   // K per block, processed as 2 halves of 256
#define BN 256       // N per block (8 waves x 32)

// out[m][n] = bias[n]  (64 x 8192 f32, as float4)
__global__ __launch_bounds__(256, 2) void nvfp4_init_out(const float* __restrict__ bias,
                                                         float* __restrict__ out) {
    int i = blockIdx.x * 256 + threadIdx.x;      // 131072 float4s
    ((f32x4*)out)[i] = ((const f32x4*)bias)[i & 2047];
}

__global__ __launch_bounds__(512, 4) void nvfp4_gemm(const float* __restrict__ x,
                                                     const int* __restrict__ wp,
                                                     const float* __restrict__ ws,
                                                     const float* __restrict__ gs,
                                                     float* __restrict__ out) {
    // LDS: x half-tile [64][256] f16 XOR-swizzled (32 KiB) + scales as packed f16x2 [256][33] u32 (33 KiB)
    __shared__ __align__(16) uint8_t xl[64 * 256 * 2];
    __shared__ uint32_t sl[256 * 33];

    const int tid = threadIdx.x;
    const int nb = blockIdx.x & 31;     // n-block 0..31
    const int ksp = blockIdx.x >> 5;    // k-split 0..15
    const int nbase = nb * BN;
    const int kc0 = ksp * KCHUNK;

    // ---- stage scales: 256 rows x 32 cols, pre-multiplied by 1/g, packed as duplicated f16x2 ----
    {
        float g = gs[0];
        float inv_g = (g != 0.0f) ? (1.0f / g) : 1.0f;
        int row = tid >> 1;             // 0..255
        int cb = (tid & 1) * 16;        // 0 or 16
        const f32x4* sp = (const f32x4*)(ws + (size_t)(nbase + row) * 512 + (kc0 >> 4) + cb);
        uint32_t* d = sl + row * 33 + cb;
        #pragma unroll
        for (int q = 0; q < 4; ++q) {
            f32x4 v = sp[q];
            float a0 = v.x * inv_g, a1 = v.y * inv_g, a2 = v.z * inv_g, a3 = v.w * inv_g;
            d[q * 4 + 0] = pkrtz(a0, a0);
            d[q * 4 + 1] = pkrtz(a1, a1);
            d[q * 4 + 2] = pkrtz(a2, a2);
            d[q * 4 + 3] = pkrtz(a3, a3);
        }
    }

    const int lane = tid & 63;
    const int wid = tid >> 6;     // 0..7
    const int l15 = lane & 15;
    const int grp = lane >> 4;    // 0..3

    // ---- x staging helper: half h (256 k) -> swizzled f16 LDS ----
    auto stage_x = [&](int h) {
        int a = tid >> 5;              // 0..15
        int cb8 = (tid & 31) * 8;      // f16 col 0..248
        const float* xp = x + (size_t)a * KTOT + kc0 + h * 256 + cb8;
        #pragma unroll
        for (int j = 0; j < 4; ++j) {
            int row = a + j * 16;
            f32x4 v0 = *(const f32x4*)(xp + (size_t)j * 16 * KTOT);
            f32x4 v1 = *(const f32x4*)(xp + (size_t)j * 16 * KTOT + 4);
            uint4 d;
            d.x = pkrtz(v0.x, v0.y);
            d.y = pkrtz(v0.z, v0.w);
            d.z = pkrtz(v1.x, v1.y);
            d.w = pkrtz(v1.z, v1.w);
            uint32_t addr = ((uint32_t)(row * 512 + cb8 * 2)) ^ ((row & 7) << 4);
            *(uint4*)(xl + addr) = d;
        }
    };

    f32x4 acc[4][2];
    #pragma unroll
    for (int a = 0; a < 4; ++a)
        #pragma unroll
        for (int b = 0; b < 2; ++b)
            acc[a][b] = f32x4{0.f, 0.f, 0.f, 0.f};

    const uint32_t TH = 0x46444240u, TL = 0x3E3C3800u;  // f16 high-byte tables for e2m1 mags

    // W row pointers for this lane's two n-strips (each int32 element = 2 weights)
    const int wrow0 = nbase + wid * 32 + l15;
    const int* wp0 = wp + (size_t)wrow0 * 4096 + (kc0 >> 1) + grp * 4;
    const int* wp1 = wp + (size_t)(wrow0 + 16) * 4096 + (kc0 >> 1) + grp * 4;
    const int srow0 = (wid * 32 + l15) * 33;
    const int srow1 = (wid * 32 + 16 + l15) * 33;

    stage_x(0);
    // prefetch W for t=0
    int4 wc0 = *(const int4*)(wp0);
    int4 wc1 = *(const int4*)(wp1);
    __syncthreads();

    #pragma unroll
    for (int t = 0; t < 16; ++t) {          // flat k-step: k = kc0 + t*32
        if (t == 8) {
            __syncthreads();                // all waves done reading half-0 xl
            stage_x(1);
            __syncthreads();
        }
        // rolling depth-1 W prefetch
        int4 wn0, wn1;
        if (t < 15) {
            wn0 = *(const int4*)(wp0 + (t + 1) * 16);
            wn1 = *(const int4*)(wp1 + (t + 1) * 16);
        }
        // A fragments from swizzled LDS (half = t>>3)
        f16x8 af[4];
        #pragma unroll
        for (int mt = 0; mt < 4; ++mt) {
            int row = mt * 16 + l15;
            uint32_t addr = ((uint32_t)(row * 512 + ((t & 7) * 32 + grp * 8) * 2)) ^ ((row & 7) << 4);
            af[mt] = *(const f16x8*)(xl + addr);
        }
        // scales (packed duplicated f16x2)
        const int scol = t * 2 + (grp >> 1);
        f16x2 s2a = bch2(sl[srow0 + scol]);
        f16x2 s2b = bch2(sl[srow1 + scol]);

        #pragma unroll
        for (int ss = 0; ss < 2; ++ss) {
            const int4 w4 = ss ? wc1 : wc0;
            const f16x2 s2 = ss ? s2b : s2a;
            uint32_t b = (uint32_t)(w4.x & 0xff) | ((uint32_t)(w4.y & 0xff) << 8) |
                         ((uint32_t)(w4.z & 0xff) << 16) | ((uint32_t)w4.w << 24);
            uint32_t sel_e = b & 0x07070707u;
            uint32_t sel_o = (b >> 4) & 0x07070707u;
            uint32_t he = perm(TH, TL, sel_e) | ((b & 0x08080808u) << 4);
            uint32_t ho = perm(TH, TL, sel_o) | (b & 0x80808080u);
            uint32_t d0 = perm(ho, he, 0x040C000Cu);
            uint32_t d1 = perm(ho, he, 0x050C010Cu);
            uint32_t d2 = perm(ho, he, 0x060C020Cu);
            uint32_t d3 = perm(ho, he, 0x070C030Cu);
            union { uint32_t u[4]; f16x8 h; } fr;
            fr.u[0] = bcu(bch2(d0) * s2);
            fr.u[1] = bcu(bch2(d1) * s2);
            fr.u[2] = bcu(bch2(d2) * s2);
            fr.u[3] = bcu(bch2(d3) * s2);
            #pragma unroll
            for (int mt = 0; mt < 4; ++mt)
                acc[mt][ss] = __builtin_amdgcn_mfma_f32_16x16x32_f16(af[mt], fr.h, acc[mt][ss], 0, 0, 0);
        }
        wc0 = wn0;
        wc1 = wn1;
    }

    // ---- epilogue: atomic-add partial tile into out ----
    #pragma unroll
    for (int mt = 0; mt < 4; ++mt)
        #pragma unroll
        for (int ss = 0; ss < 2; ++ss)
            #pragma unroll
            for (int q = 0; q < 4; ++q) {
                int row = mt * 16 + grp * 4 + q;
                int col = nbase + wid * 32 + ss * 16 + l15;
                unsafeAtomicAdd(out + (size_t)row * NTOT + col, acc[mt][ss][q]);
            }
}

extern "C" void kernel_launch(void* const* d_in, const int* in_sizes, int n_in,
                              void* d_out, int out_size, void* d_ws, size_t ws_size,
                              hipStream_t stream) {
    const float* x = (const float*)d_in[0];
    const int* wp = (const int*)d_in[1];
    const float* ws = (const float*)d_in[2];
    const float* gs = (const float*)d_in[3];
    const float* bias = (const float*)d_in[4];
    float* out = (float*)d_out;

    nvfp4_init_out<<<dim3(512), dim3(256), 0, stream>>>(bias, out);
    nvfp4_gemm<<<dim3(SPLITS * (NTOT / BN)), dim3(512), 0, stream>>>(x, wp, ws, gs, out);
}

// Round 7
// 221.401 us; speedup vs baseline: 1.0645x; 1.0645x over previous
//
#include <hip/hip_runtime.h>
#include <stdint.h>

typedef _Float16 f16x2 __attribute__((ext_vector_type(2)));
typedef _Float16 f16x8 __attribute__((ext_vector_type(8)));
typedef float f32x4 __attribute__((ext_vector_type(4)));

static __device__ __forceinline__ uint32_t perm(uint32_t hi, uint32_t lo, uint32_t sel) {
    return __builtin_amdgcn_perm(hi, lo, sel);
}
static __device__ __forceinline__ f16x2 bch2(uint32_t u) { union { uint32_t x; f16x2 h; } c; c.x = u; return c.h; }
static __device__ __forceinline__ uint32_t bcu(f16x2 h) { union { uint32_t x; f16x2 h; } c; c.h = h; return c.x; }
// cvt_pkrtz returns __fp16x2 (distinct from _Float16x2) — bit-cast through its own type
static __device__ __forceinline__ uint32_t pkrtz(float a, float b) {
    auto r = __builtin_amdgcn_cvt_pkrtz(a, b);
    union { decltype(r) h; uint32_t u; } c; c.h = r; return c.u;
}

#define NTOT 8192
#define KTOT 8192
#define SPLITS 8
#define KCHUNK 1024   // K per block: 4 quarters of 256
#define BN 256        // N per block (8 waves x 32)
#define QK 256        // k per quarter

// out[m][n] = bias[n]  (atomic-fallback path only)
__global__ __launch_bounds__(256, 2) void nvfp4_init_out(const float* __restrict__ bias,
                                                         float* __restrict__ out) {
    int i = blockIdx.x * 256 + threadIdx.x;      // 131072 float4s
    ((f32x4*)out)[i] = ((const f32x4*)bias)[i & 2047];
}

// out[m][n] = bias[n] + sum_s part[s][m][n]
__global__ __launch_bounds__(256, 2) void nvfp4_reduce(const float* __restrict__ part,
                                                       const float* __restrict__ bias,
                                                       float* __restrict__ out) {
    int i = blockIdx.x * 256 + threadIdx.x;      // 0..131071 f32x4 index
    f32x4 s = ((const f32x4*)bias)[i & 2047];
    #pragma unroll
    for (int p = 0; p < SPLITS; ++p) {
        f32x4 v = ((const f32x4*)part)[(size_t)p * 131072 + i];
        s = s + v;
    }
    ((f32x4*)out)[i] = s;
}

__global__ __launch_bounds__(512, 2) void nvfp4_gemm(const float* __restrict__ x,
                                                     const int* __restrict__ wp,
                                                     const float* __restrict__ wscale,
                                                     const float* __restrict__ gs,
                                                     float* __restrict__ dst,
                                                     int atomic_mode) {
    // LDS: x quarter-tiles double-buffered, XOR-swizzled f16 (2 x 32 KiB)
    //      + scales as duplicated-f16x2 u32 [256][65] (66.6 KiB)  => ~129 KiB, 1 block/CU
    __shared__ __align__(16) uint8_t xl[2][64 * 256 * 2];
    __shared__ uint32_t sl[256 * 65];

    const int tid = threadIdx.x;
    const int nb = blockIdx.x & 31;     // n-block 0..31
    const int ksp = blockIdx.x >> 5;    // k-split 0..7
    const int nbase = nb * BN;
    const int kc0 = ksp * KCHUNK;

    // ---- stage scales: 256 rows x 64 cols, pre-multiplied by 1/g, packed as duplicated f16x2 ----
    {
        float g = gs[0];
        float inv_g = (g != 0.0f) ? (1.0f / g) : 1.0f;
        int row = tid >> 1;             // 0..255
        int cb = (tid & 1) * 32;        // 0 or 32
        const f32x4* sp = (const f32x4*)(wscale + (size_t)(nbase + row) * 512 + ksp * 64 + cb);
        uint32_t* d = sl + row * 65 + cb;
        #pragma unroll
        for (int q = 0; q < 8; ++q) {
            f32x4 v = sp[q];
            float a0 = v.x * inv_g, a1 = v.y * inv_g, a2 = v.z * inv_g, a3 = v.w * inv_g;
            d[q * 4 + 0] = pkrtz(a0, a0);
            d[q * 4 + 1] = pkrtz(a1, a1);
            d[q * 4 + 2] = pkrtz(a2, a2);
            d[q * 4 + 3] = pkrtz(a3, a3);
        }
    }

    const int lane = tid & 63;
    const int wid = tid >> 6;     // 0..7
    const int l15 = lane & 15;
    const int grp = lane >> 4;    // 0..3

    // ---- x staging: issue-early loads into regs, write-late to LDS (T14) ----
    const int sa = tid >> 5;            // 0..15
    const int scb = (tid & 31) * 8;     // f16 col 0..248
    const float* xbase = x + (size_t)sa * KTOT + kc0 + scb;

    auto xload = [&](int q, f32x4* r) {
        const float* p = xbase + q * QK;
        #pragma unroll
        for (int j = 0; j < 4; ++j) {
            r[j * 2 + 0] = *(const f32x4*)(p + (size_t)j * 16 * KTOT);
            r[j * 2 + 1] = *(const f32x4*)(p + (size_t)j * 16 * KTOT + 4);
        }
    };
    auto xwrite = [&](int b, const f32x4* r) {
        #pragma unroll
        for (int j = 0; j < 4; ++j) {
            int row = sa + j * 16;
            uint4 d;
            d.x = pkrtz(r[j * 2].x, r[j * 2].y);
            d.y = pkrtz(r[j * 2].z, r[j * 2].w);
            d.z = pkrtz(r[j * 2 + 1].x, r[j * 2 + 1].y);
            d.w = pkrtz(r[j * 2 + 1].z, r[j * 2 + 1].w);
            uint32_t addr = ((uint32_t)(row * 512 + scb * 2)) ^ ((row & 7) << 4);
            *(uint4*)(xl[b] + addr) = d;
        }
    };

    f32x4 acc[4][2];
    #pragma unroll
    for (int a = 0; a < 4; ++a)
        #pragma unroll
        for (int b = 0; b < 2; ++b)
            acc[a][b] = f32x4{0.f, 0.f, 0.f, 0.f};

    const uint32_t TH = 0x46444240u, TL = 0x3E3C3800u;  // f16 high-byte tables for e2m1 mags

    // W row pointers for this lane's two n-strips (each int32 element = 2 weights)
    const int wrow0 = nbase + wid * 32 + l15;
    const int* wq0 = wp + (size_t)wrow0 * 4096 + (kc0 >> 1) + grp * 4;
    const int* wq1 = wp + (size_t)(wrow0 + 16) * 4096 + (kc0 >> 1) + grp * 4;
    const int srow0 = (wid * 32 + l15) * 65;
    const int srow1 = (wid * 32 + 16 + l15) * 65;

    // ---- prologue: stage q0, issue q1, prefetch W t=0,1 ----
    f32x4 sA[8], sB[8];
    xload(0, sA);
    int4 w0[3], w1[3];                 // rolling depth-2 W prefetch (static idx under full unroll)
    w0[0] = *(const int4*)(wq0);
    w1[0] = *(const int4*)(wq1);
    w0[1] = *(const int4*)(wq0 + 16);
    w1[1] = *(const int4*)(wq1 + 16);
    xwrite(0, sA);
    xload(1, sB);
    __syncthreads();

    #pragma unroll
    for (int t = 0; t < 32; ++t) {          // k = kc0 + t*32
        const int rb = (t >> 3) & 1;        // read buffer
        const int tq = t & 7;
        // issue W prefetch for t+2
        if (t < 30) {
            w0[(t + 2) % 3] = *(const int4*)(wq0 + (t + 2) * 16);
            w1[(t + 2) % 3] = *(const int4*)(wq1 + (t + 2) * 16);
        }
        // A fragments from swizzled LDS
        f16x8 af[4];
        #pragma unroll
        for (int mt = 0; mt < 4; ++mt) {
            int row = mt * 16 + l15;
            uint32_t addr = ((uint32_t)(row * 512 + (tq * 32 + grp * 8) * 2)) ^ ((row & 7) << 4);
            af[mt] = *(const f16x8*)(xl[rb] + addr);
        }
        // scales (packed duplicated f16x2)
        const int scol = t * 2 + (grp >> 1);
        f16x2 s2a = bch2(sl[srow0 + scol]);
        f16x2 s2b = bch2(sl[srow1 + scol]);

        #pragma unroll
        for (int ss = 0; ss < 2; ++ss) {
            const int4 w4 = ss ? w1[t % 3] : w0[t % 3];
            const f16x2 s2 = ss ? s2b : s2a;
            uint32_t b = (uint32_t)(w4.x & 0xff) | ((uint32_t)(w4.y & 0xff) << 8) |
                         ((uint32_t)(w4.z & 0xff) << 16) | ((uint32_t)w4.w << 24);
            uint32_t sel_e = b & 0x07070707u;
            uint32_t sel_o = (b >> 4) & 0x07070707u;
            uint32_t he = perm(TH, TL, sel_e) | ((b & 0x08080808u) << 4);
            uint32_t ho = perm(TH, TL, sel_o) | (b & 0x80808080u);
            uint32_t d0 = perm(ho, he, 0x040C000Cu);
            uint32_t d1 = perm(ho, he, 0x050C010Cu);
            uint32_t d2 = perm(ho, he, 0x060C020Cu);
            uint32_t d3 = perm(ho, he, 0x070C030Cu);
            union { uint32_t u[4]; f16x8 h; } fr;
            fr.u[0] = bcu(bch2(d0) * s2);
            fr.u[1] = bcu(bch2(d1) * s2);
            fr.u[2] = bcu(bch2(d2) * s2);
            fr.u[3] = bcu(bch2(d3) * s2);
            #pragma unroll
            for (int mt = 0; mt < 4; ++mt)
                acc[mt][ss] = __builtin_amdgcn_mfma_f32_16x16x32_f16(af[mt], fr.h, acc[mt][ss], 0, 0, 0);
        }

        // end-of-quarter: write next quarter's staged x, issue quarter+2 loads
        if ((t & 7) == 7 && t < 31) {
            const int q = t >> 3;           // completed quarter 0,1,2
            if (q == 0) { xwrite(1, sB); xload(2, sA); }
            if (q == 1) { xwrite(0, sA); xload(3, sB); }
            if (q == 2) { xwrite(1, sB); }
            __syncthreads();
        }
    }

    // ---- epilogue ----
    if (atomic_mode) {
        #pragma unroll
        for (int mt = 0; mt < 4; ++mt)
            #pragma unroll
            for (int ss = 0; ss < 2; ++ss)
                #pragma unroll
                for (int q = 0; q < 4; ++q) {
                    int row = mt * 16 + grp * 4 + q;
                    int col = nbase + wid * 32 + ss * 16 + l15;
                    unsafeAtomicAdd(dst + (size_t)row * NTOT + col, acc[mt][ss][q]);
                }
    } else {
        float* pd = dst + (size_t)ksp * 64 * NTOT;
        #pragma unroll
        for (int mt = 0; mt < 4; ++mt)
            #pragma unroll
            for (int ss = 0; ss < 2; ++ss)
                #pragma unroll
                for (int q = 0; q < 4; ++q) {
                    int row = mt * 16 + grp * 4 + q;
                    int col = nbase + wid * 32 + ss * 16 + l15;
                    pd[(size_t)row * NTOT + col] = acc[mt][ss][q];
                }
    }
}

extern "C" void kernel_launch(void* const* d_in, const int* in_sizes, int n_in,
                              void* d_out, int out_size, void* d_ws, size_t ws_size,
                              hipStream_t stream) {
    const float* x = (const float*)d_in[0];
    const int* wp = (const int*)d_in[1];
    const float* wscale = (const float*)d_in[2];
    const float* gs = (const float*)d_in[3];
    const float* bias = (const float*)d_in[4];
    float* out = (float*)d_out;

    const size_t need = (size_t)SPLITS * 64 * NTOT * sizeof(float);   // 16 MiB
    if (ws_size >= need) {
        nvfp4_gemm<<<dim3(SPLITS * (NTOT / BN)), dim3(512), 0, stream>>>(x, wp, wscale, gs, (float*)d_ws, 0);
        nvfp4_reduce<<<dim3(512), dim3(256), 0, stream>>>((const float*)d_ws, bias, out);
    } else {
        nvfp4_init_out<<<dim3(512), dim3(256), 0, stream>>>(bias, out);
        nvfp4_gemm<<<dim3(SPLITS * (NTOT / BN)), dim3(512), 0, stream>>>(x, wp, wscale, gs, out, 1);
    }
}

// Round 8
// 220.214 us; speedup vs baseline: 1.0702x; 1.0054x over previous
//
#include <hip/hip_runtime.h>
#include <stdint.h>

typedef _Float16 f16x2 __attribute__((ext_vector_type(2)));
typedef _Float16 f16x8 __attribute__((ext_vector_type(8)));
typedef float f32x4 __attribute__((ext_vector_type(4)));

static __device__ __forceinline__ uint32_t perm(uint32_t hi, uint32_t lo, uint32_t sel) {
    return __builtin_amdgcn_perm(hi, lo, sel);
}
static __device__ __forceinline__ f16x2 bch2(uint32_t u) { union { uint32_t x; f16x2 h; } c; c.x = u; return c.h; }
static __device__ __forceinline__ uint32_t bcu(f16x2 h) { union { uint32_t x; f16x2 h; } c; c.h = h; return c.x; }
static __device__ __forceinline__ uint32_t pkrtz(float a, float b) {
    auto r = __builtin_amdgcn_cvt_pkrtz(a, b);
    union { decltype(r) h; uint32_t u; } c; c.h = r; return c.u;
}

#define NTOT 8192
#define KTOT 8192
#define SPLITS 8
#define KCHUNK 1024   // K per block: 8 periods of 128
#define BN 256        // N per block (8 waves x 32)
#define PK 128        // k per staging period
#define NPER (KCHUNK / PK)

// out[m][n] = bias[n]  (atomic-fallback path only)
__global__ __launch_bounds__(256, 2) void nvfp4_init_out(const float* __restrict__ bias,
                                                         float* __restrict__ out) {
    int i = blockIdx.x * 256 + threadIdx.x;
    ((f32x4*)out)[i] = ((const f32x4*)bias)[i & 2047];
}

// out[m][n] = bias[n] + sum_s part[s][m][n]
__global__ __launch_bounds__(256, 2) void nvfp4_reduce(const float* __restrict__ part,
                                                       const float* __restrict__ bias,
                                                       float* __restrict__ out) {
    int i = blockIdx.x * 256 + threadIdx.x;
    f32x4 s = ((const f32x4*)bias)[i & 2047];
    #pragma unroll
    for (int p = 0; p < SPLITS; ++p) {
        f32x4 v = ((const f32x4*)part)[(size_t)p * 131072 + i];
        s = s + v;
    }
    ((f32x4*)out)[i] = s;
}

__global__ __launch_bounds__(512, 2) void nvfp4_gemm(const float* __restrict__ x,
                                                     const int* __restrict__ wp,
                                                     const float* __restrict__ wscale,
                                                     const float* __restrict__ gs,
                                                     float* __restrict__ dst,
                                                     int atomic_mode) {
    // LDS (98 KiB total):
    //  wl : compacted packed W, [buf][256 rows][16 u32] (16 words = 64 B = 128 weights), XOR-swizzled. 2x16 KiB
    //  xtl: x as f16, [buf][64 rows][256 B] (128 f16), 16B-slot XOR-swizzled.                        2x16 KiB
    //  scl: scales as f16, [256 rows][66] stride-66 (33-word stride => conflict-free).               33 KiB
    __shared__ uint32_t wl[2][256 * 16];
    __shared__ __align__(16) uint8_t xtl[2][64 * 256];
    __shared__ uint16_t scl[256 * 66];

    const int tid = threadIdx.x;
    const int nb = blockIdx.x & 31;     // n-block 0..31
    const int ksp = blockIdx.x >> 5;    // k-split 0..7
    const int nbase = nb * BN;
    const int kc0 = ksp * KCHUNK;

    const int lane = tid & 63;
    const int wid = tid >> 6;     // 0..7
    const int l15 = lane & 15;
    const int grp = lane >> 4;    // 0..3

    // ---- staging maps ----
    // W: thread -> (row = (tid>>4) + i*32, 16B int4-slot s = tid&15). Wave footprint per instr:
    //    4 rows x 256 contiguous B (2 full lines/row). Compacts 16 input B -> 4 packed B.
    const int wsrow = tid >> 4;
    const int wss = tid & 15;
    const int* wgp = wp + (size_t)(nbase + wsrow) * 4096 + (kc0 >> 1) + wss * 4;
    // x: thread -> (row = tid>>3, 16B slot s8 = tid&7). Wave footprint: 8 rows x 128 contiguous B.
    const int xsrow = tid >> 3;
    const int xss = tid & 7;
    const float* xgp = x + (size_t)xsrow * KTOT + kc0 + xss * 4;

    int4 wst[8];
    f32x4 xst[4];

    auto issueW = [&](int p) {
        #pragma unroll
        for (int i = 0; i < 8; ++i)
            wst[i] = *(const int4*)(wgp + (size_t)i * 32 * 4096 + p * 64);
    };
    auto issueX = [&](int p) {
        #pragma unroll
        for (int j = 0; j < 4; ++j)
            xst[j] = *(const f32x4*)(xgp + p * 128 + j * 32);
    };
    auto writeW = [&](int p) {
        uint32_t* wb = wl[p & 1];
        #pragma unroll
        for (int i = 0; i < 8; ++i) {
            int R = wsrow + i * 32;
            uint32_t v = (uint32_t)(wst[i].x & 0xff) | ((uint32_t)(wst[i].y & 0xff) << 8) |
                         ((uint32_t)(wst[i].z & 0xff) << 16) | ((uint32_t)wst[i].w << 24);
            wb[R * 16 + (wss ^ (R & 15))] = v;       // word-in-row swizzle
        }
    };
    auto writeX = [&](int p) {
        uint8_t* xb = xtl[p & 1];
        #pragma unroll
        for (int j = 0; j < 4; ++j) {
            uint32_t lo = pkrtz(xst[j].x, xst[j].y);
            uint32_t hi = pkrtz(xst[j].z, xst[j].w);
            int slot = j * 4 + (xss >> 1);
            uint32_t addr = (uint32_t)(xsrow * 256 + ((slot ^ (xsrow & 15)) << 4) + (xss & 1) * 8);
            uint2 dv; dv.x = lo; dv.y = hi;
            *(uint2*)(xb + addr) = dv;               // 16B-slot swizzle
        }
    };

    // ---- prologue: issue period 0, stage scales while loads fly, then write period 0 ----
    issueW(0);
    issueX(0);
    {
        float g = gs[0];
        float inv_g = (g != 0.0f) ? (1.0f / g) : 1.0f;
        int row = tid >> 1;
        int half = tid & 1;
        const float* sp = wscale + (size_t)(nbase + row) * 512 + (kc0 >> 4) + half * 32;
        #pragma unroll
        for (int j = 0; j < 8; ++j) {
            f32x4 v = *(const f32x4*)(sp + j * 4);
            uint32_t p01 = pkrtz(v.x * inv_g, v.y * inv_g);
            uint32_t p23 = pkrtz(v.z * inv_g, v.w * inv_g);
            uint32_t c = half * 32 + j * 4;
            *(uint32_t*)((uint8_t*)scl + row * 132 + c * 2) = p01;
            *(uint32_t*)((uint8_t*)scl + row * 132 + c * 2 + 4) = p23;
        }
    }
    writeW(0);
    writeX(0);
    __syncthreads();

    f32x4 acc[4][2];
    #pragma unroll
    for (int a = 0; a < 4; ++a)
        #pragma unroll
        for (int b = 0; b < 2; ++b)
            acc[a][b] = f32x4{0.f, 0.f, 0.f, 0.f};

    const uint32_t TH = 0x46444240u, TL = 0x3E3C3800u;  // f16 high-byte tables for e2m1 mags
    const int srowb0 = (wid * 32 + l15) * 132;
    const int srowb1 = (wid * 32 + 16 + l15) * 132;
    const int wR0 = wid * 32 + l15;          // strip-0 row (R&15 == l15)
    const int wR1 = wid * 32 + 16 + l15;     // strip-1 row

    for (int p = 0; p < NPER; ++p) {
        if (p + 1 < NPER) { issueW(p + 1); issueX(p + 1); }   // T14: issue early
        const uint32_t* wb = wl[p & 1];
        const uint8_t* xb = xtl[p & 1];

        #pragma unroll
        for (int tl = 0; tl < 4; ++tl) {
            // x fragments (swizzled b128)
            f16x8 af[4];
            #pragma unroll
            for (int mt = 0; mt < 4; ++mt) {
                int row = mt * 16 + l15;
                uint32_t addr = (uint32_t)(row * 256 + (((tl * 4 + grp) ^ l15) << 4));
                af[mt] = *(const f16x8*)(xb + addr);
            }
            // scales (f16, duplicated via perm)
            int scol = p * 8 + tl * 2 + (grp >> 1);
            uint32_t sr0 = *(const uint16_t*)((const uint8_t*)scl + srowb0 + scol * 2);
            uint32_t sr1 = *(const uint16_t*)((const uint8_t*)scl + srowb1 + scol * 2);
            f16x2 s2a = bch2(perm(0, sr0, 0x01000100u));
            f16x2 s2b = bch2(perm(0, sr1, 0x01000100u));

            #pragma unroll
            for (int ss = 0; ss < 2; ++ss) {
                const int R = ss ? wR1 : wR0;
                const f16x2 s2 = ss ? s2b : s2a;
                uint32_t b = wb[R * 16 + ((tl * 4 + grp) ^ l15)];   // 4 B = 8 weights
                uint32_t sel_e = b & 0x07070707u;
                uint32_t sel_o = (b >> 4) & 0x07070707u;
                uint32_t he = perm(TH, TL, sel_e) | ((b & 0x08080808u) << 4);
                uint32_t ho = perm(TH, TL, sel_o) | (b & 0x80808080u);
                uint32_t d0 = perm(ho, he, 0x040C000Cu);
                uint32_t d1 = perm(ho, he, 0x050C010Cu);
                uint32_t d2 = perm(ho, he, 0x060C020Cu);
                uint32_t d3 = perm(ho, he, 0x070C030Cu);
                union { uint32_t u[4]; f16x8 h; } fr;
                fr.u[0] = bcu(bch2(d0) * s2);
                fr.u[1] = bcu(bch2(d1) * s2);
                fr.u[2] = bcu(bch2(d2) * s2);
                fr.u[3] = bcu(bch2(d3) * s2);
                #pragma unroll
                for (int mt = 0; mt < 4; ++mt)
                    acc[mt][ss] = __builtin_amdgcn_mfma_f32_16x16x32_f16(af[mt], fr.h, acc[mt][ss], 0, 0, 0);
            }
        }

        if (p + 1 < NPER) { writeW(p + 1); writeX(p + 1); }   // write late
        __syncthreads();
    }

    // ---- epilogue ----
    if (atomic_mode) {
        #pragma unroll
        for (int mt = 0; mt < 4; ++mt)
            #pragma unroll
            for (int ss = 0; ss < 2; ++ss)
                #pragma unroll
                for (int q = 0; q < 4; ++q) {
                    int row = mt * 16 + grp * 4 + q;
                    int col = nbase + wid * 32 + ss * 16 + l15;
                    unsafeAtomicAdd(dst + (size_t)row * NTOT + col, acc[mt][ss][q]);
                }
    } else {
        float* pd = dst + (size_t)ksp * 64 * NTOT;
        #pragma unroll
        for (int mt = 0; mt < 4; ++mt)
            #pragma unroll
            for (int ss = 0; ss < 2; ++ss)
                #pragma unroll
                for (int q = 0; q < 4; ++q) {
                    int row = mt * 16 + grp * 4 + q;
                    int col = nbase + wid * 32 + ss * 16 + l15;
                    pd[(size_t)row * NTOT + col] = acc[mt][ss][q];
                }
    }
}

extern "C" void kernel_launch(void* const* d_in, const int* in_sizes, int n_in,
                              void* d_out, int out_size, void* d_ws, size_t ws_size,
                              hipStream_t stream) {
    const float* x = (const float*)d_in[0];
    const int* wp = (const int*)d_in[1];
    const float* wscale = (const float*)d_in[2];
    const float* gs = (const float*)d_in[3];
    const float* bias = (const float*)d_in[4];
    float* out = (float*)d_out;

    const size_t need = (size_t)SPLITS * 64 * NTOT * sizeof(float);   // 16 MiB
    if (ws_size >= need) {
        nvfp4_gemm<<<dim3(SPLITS * (NTOT / BN)), dim3(512), 0, stream>>>(x, wp, wscale, gs, (float*)d_ws, 0);
        nvfp4_reduce<<<dim3(512), dim3(256), 0, stream>>>((const float*)d_ws, bias, out);
    } else {
        nvfp4_init_out<<<dim3(512), dim3(256), 0, stream>>>(bias, out);
        nvfp4_gemm<<<dim3(SPLITS * (NTOT / BN)), dim3(512), 0, stream>>>(x, wp, wscale, gs, out, 1);
    }
}